// Round 8
// baseline (22.068 us; speedup 1.0000x reference)
//
#include <hip/hip_runtime.h>

#define NN 1024
#define DD 128

typedef float f32x4 __attribute__((ext_vector_type(4)));
typedef _Float16 f16x8 __attribute__((ext_vector_type(8)));

__device__ __forceinline__ f16x8 cvt8(f32x4 a, f32x4 b) {
  f16x8 r;
  r[0] = (_Float16)a.x; r[1] = (_Float16)a.y; r[2] = (_Float16)a.z; r[3] = (_Float16)a.w;
  r[4] = (_Float16)b.x; r[5] = (_Float16)b.y; r[6] = (_Float16)b.z; r[7] = (_Float16)b.w;
  return r;
}

// ws layout (f32 units):
//   [0 .. 16384)               S[js][i]        (16 x 1024)
//   [16384 .. 16384+2097152)   part[js][i][d]  (16 x 1024 x 128)
#define WS_S 16384
#define YP 72   // padded row length (f16) for Ytp/KsT: 144B rows -> 2-way-free banks

// Grid (16 js, 64 ib) = 1024 blocks x 4 waves = 4096 waves (4/SIMD, all resident).
// Wave w: phase A owns j-window js*64+w*16..+16 (QK^T swapped: lane=col=i,
// A-rows = Y window rows; writes f16 Y^T into block tile Ytp). Block-level
// per-i scale via msc (barrier 1), K'^T into KsT (barrier 2). Phase D: wave w
// owns d-range w*32..+32, contracting the block's full 64 j with
// mfma(KsT-frag, Ytp-frag) -> D[i][d], d along lanes -> coalesced slab stores.
__global__ __launch_bounds__(256, 4) void gk_main(const float* __restrict__ X,
                                                  const float* __restrict__ Y,
                                                  const int* __restrict__ hp,
                                                  float* __restrict__ out,
                                                  float* __restrict__ ws) {
  __shared__ __align__(16) _Float16 Ytp[128 * YP];  // [d][j-local], 18 KB
  __shared__ __align__(16) _Float16 KsT[16 * YP];   // [i-local][j-local], 2.25 KB
  __shared__ unsigned msc[16];
  __shared__ float Sred[16];

  const int tid  = threadIdx.x;
  const int js   = blockIdx.x;          // 0..15  (j block of 64)
  const int ib   = blockIdx.y;          // 0..63  (i block of 16)
  const int lane = tid & 63;
  const int w    = tid >> 6;            // wave 0..3
  const int g    = lane >> 4;           // k-group 0..3
  const int li   = lane & 15;

  const float fh = (float)hp[0];
  const float inv_h2 = 1.0f / (fh * fh);

  if (tid < 16) { msc[tid] = 0u; Sred[tid] = 0.0f; }

  // ---- X fragments + |x|^2 (per-lane row li of the i-tile) ----
  const float* Xr = X + (size_t)(ib * 16 + li) * DD;
  f32x4 xa[4][2];
  float xx = 0.f;
  #pragma unroll
  for (int kt = 0; kt < 4; ++kt) {
    int d0 = kt * 32 + g * 8;
    xa[kt][0] = *(const f32x4*)(Xr + d0);
    xa[kt][1] = *(const f32x4*)(Xr + d0 + 4);
    #pragma unroll
    for (int c = 0; c < 4; ++c)
      xx += xa[kt][0][c] * xa[kt][0][c] + xa[kt][1][c] * xa[kt][1][c];
  }
  xx += __shfl_xor(xx, 16); xx += __shfl_xor(xx, 32);

  // ---- Phase A: QK^T over own 16-j window + f16 Y^T into block LDS ----
  const float* Yr = Y + (size_t)(js * 64 + w * 16 + li) * DD;
  f32x4 acc = {0.f, 0.f, 0.f, 0.f};
  float yy = 0.f;
  const int jcol = w * 16 + li;         // block-local j owned by this lane
  #pragma unroll
  for (int kt = 0; kt < 4; ++kt) {
    int d0 = kt * 32 + g * 8;
    f32x4 a0 = *(const f32x4*)(Yr + d0), a1 = *(const f32x4*)(Yr + d0 + 4);
    #pragma unroll
    for (int c = 0; c < 4; ++c) yy += a0[c] * a0[c] + a1[c] * a1[c];
    f16x8 af = cvt8(a0, a1);
    // Y^T writes, c-order rotated by g so the 4 g-rows hit banks {0,8,16,24}
    #pragma unroll
    for (int cc = 0; cc < 8; ++cc) {
      int c = (cc + 2 * g) & 7;
      Ytp[(d0 + c) * YP + jcol] = af[c];
    }
    acc = __builtin_amdgcn_mfma_f32_16x16x32_f16(af, cvt8(xa[kt][0], xa[kt][1]),
                                                 acc, 0, 0, 0);
  }
  yy += __shfl_xor(yy, 16); yy += __shfl_xor(yy, 32);

  // ---- exp: K[r] = K[j = w*16+4g+r][i = li] ----
  float K[4];
  float m = 0.f, sp = 0.f;
  #pragma unroll
  for (int r = 0; r < 4; ++r) {
    float yyj = __shfl(yy, 4 * g + r);       // lane 4g+r holds row (w*16+4g+r)'s norm
    float e = fminf((acc[r] - 0.5f * (xx + yyj)) * inv_h2, 0.0f);
    K[r] = exp2f(e * 1.44269504088896341f);
    m = fmaxf(m, K[r]); sp += K[r];
  }
  // K store: 16 i-rows x 4 g-quads = full 64B segments per row
  {
    float* kb = out + (size_t)(ib * 16 + li) * NN + js * 64 + w * 16 + 4 * g;
    f32x4 kv = { K[0], K[1], K[2], K[3] };
    *(f32x4*)kb = kv;
  }
  // per-i (col) stats over this wave's 16 j, then block-wide via LDS atomics
  m = fmaxf(m, __shfl_xor(m, 16)); m = fmaxf(m, __shfl_xor(m, 32));
  sp += __shfl_xor(sp, 16);        sp += __shfl_xor(sp, 32);
  if (lane < 16) {
    atomicMax(&msc[li], __float_as_uint(m));
    atomicAdd(&Sred[li], sp);
  }
  __syncthreads();   // bar1: msc/Sred final, Ytp complete

  if (tid < 16) ws[(size_t)js * NN + ib * 16 + tid] = Sred[tid];

  // ---- K'^T (f16, scaled per-i) into KsT[i][j-local] ----
  {
    unsigned ue = (msc[li] >> 23) & 0xffu;
    unsigned se = 266u - ue; if (se > 254u) se = 254u;  // K'max in [2^12,2^13)
    float scale = __uint_as_float(se << 23);
    #pragma unroll
    for (int r = 0; r < 4; ++r)
      KsT[li * YP + w * 16 + 4 * g + r] = (_Float16)(K[r] * scale);
  }
  __syncthreads();   // bar2: KsT ready

  // ---- Phase D: D[i][d] = sum_{j=0..63} K'[j][i] * Y[j][d], wave d-range w*32..+32 ----
  f32x4 c0 = {0.f, 0.f, 0.f, 0.f}, c1 = {0.f, 0.f, 0.f, 0.f};
  #pragma unroll
  for (int kt = 0; kt < 2; ++kt) {
    int jb = kt * 32 + g * 8;
    f16x8 afK = *(const f16x8*)(KsT + li * YP + jb);                    // A[m=i=li][k=j]
    f16x8 b0  = *(const f16x8*)(Ytp + (w * 32 + li) * YP + jb);        // B[k=j][n=d]
    f16x8 b1  = *(const f16x8*)(Ytp + (w * 32 + 16 + li) * YP + jb);
    c0 = __builtin_amdgcn_mfma_f32_16x16x32_f16(afK, b0, c0, 0, 0, 0);
    c1 = __builtin_amdgcn_mfma_f32_16x16x32_f16(afK, b1, c1, 0, 0, 0);
  }

  // ---- epilogue: unscale per output-row i = 4g+r; coalesced slab stores ----
  float* pb = ws + WS_S + (size_t)js * (NN * DD) + (size_t)(ib * 16) * DD;
  #pragma unroll
  for (int r = 0; r < 4; ++r) {
    int il = 4 * g + r;
    unsigned ue2 = (msc[il] >> 23) & 0xffu;
    unsigned se2 = 266u - ue2; if (se2 > 254u) se2 = 254u;
    float invs = __uint_as_float((254u - se2) << 23);   // 1/scale for row il
    pb[il * DD + w * 32 + li]      = c0[r] * invs;      // 4 rows x 64B runs
    pb[il * DD + w * 32 + 16 + li] = c1[r] * invs;
  }
}

// dK[i][d] = inv_h2 * (sum_js part[js][i][d] - (sum_js S[js][i]) * X[i][d])
__global__ __launch_bounds__(256) void dk_reduce(const float* __restrict__ X,
                                                 const int* __restrict__ hp,
                                                 const float* __restrict__ ws,
                                                 float* __restrict__ out) {
  const int unit = blockIdx.x * 256 + threadIdx.x;   // 0..32767 (f32x4 units)
  const int i  = unit >> 5;
  const int d0 = (unit & 31) * 4;
  const float fh = (float)hp[0];
  const float inv_h2 = 1.0f / (fh * fh);

  f32x4 acc = {0.f, 0.f, 0.f, 0.f};
  float s = 0.f;
  #pragma unroll
  for (int js = 0; js < 16; ++js) {
    f32x4 p = *(const f32x4*)(ws + WS_S + (size_t)js * (NN * DD) + (size_t)i * DD + d0);
    acc.x += p.x; acc.y += p.y; acc.z += p.z; acc.w += p.w;
    s += ws[(size_t)js * NN + i];
  }
  f32x4 xv = *(const f32x4*)(X + (size_t)i * DD + d0);
  f32x4 r;
  r.x = (acc.x - s * xv.x) * inv_h2;
  r.y = (acc.y - s * xv.y) * inv_h2;
  r.z = (acc.z - s * xv.z) * inv_h2;
  r.w = (acc.w - s * xv.w) * inv_h2;
  *(f32x4*)(out + (size_t)NN * NN + (size_t)i * DD + d0) = r;
}

extern "C" void kernel_launch(void* const* d_in, const int* in_sizes, int n_in,
                              void* d_out, int out_size, void* d_ws, size_t ws_size,
                              hipStream_t stream) {
  const float* X  = (const float*)d_in[0];
  const float* Y  = (const float*)d_in[1];
  const int*   hp = (const int*)d_in[2];
  float* out = (float*)d_out;
  float* ws  = (float*)d_ws;    // needs (16384 + 2097152) f32 ≈ 8.5 MB

  hipLaunchKernelGGL(gk_main, dim3(16, 64), dim3(256), 0, stream, X, Y, hp, out, ws);
  hipLaunchKernelGGL(dk_reduce, dim3(128), dim3(256), 0, stream, X, hp, ws, out);
}

// Round 9
// 19.557 us; speedup vs baseline: 1.1284x; 1.1284x over previous
//
#include <hip/hip_runtime.h>

#define NN 1024
#define DD 128

typedef float f32x4 __attribute__((ext_vector_type(4)));
typedef _Float16 f16x4 __attribute__((ext_vector_type(4)));
typedef _Float16 f16x8 __attribute__((ext_vector_type(8)));

__device__ __forceinline__ f16x8 cvt8(f32x4 a, f32x4 b) {
  f16x8 r;
  r[0] = (_Float16)a.x; r[1] = (_Float16)a.y; r[2] = (_Float16)a.z; r[3] = (_Float16)a.w;
  r[4] = (_Float16)b.x; r[5] = (_Float16)b.y; r[6] = (_Float16)b.z; r[7] = (_Float16)b.w;
  return r;
}

// ws layout (f32 units):
//   [0 .. 8192)            S[js][i]        (8 x 1024)
//   [8192 .. 8192+1048576) part[js][i][d]  (8 x 1024 x 128)
#define WS_PART 8192

// R4 structure with 2x thread-level parallelism: grid (8 js, 64 ib), but
// 512 threads = 8 waves/block -> 4096 waves total = 4 waves/SIMD, whole grid
// resident (2 blocks/CU). Wave w owns j-window js*128+w*16..+16 for QK^T
// (swapped: lane=col=i, regs=row=j; ONE 16x16x32 MFMA) and d-range
// w*16..+16 for phase D (4 MFMAs over the block's 128 j). Same 8 ws slabs,
// same numerics as R4 (block-consistent per-i dynamic f16 scale).
__global__ __launch_bounds__(512, 4) void gk_main(const float* __restrict__ X,
                                                  const float* __restrict__ Y,
                                                  const int* __restrict__ hp,
                                                  float* __restrict__ out,
                                                  float* __restrict__ ws) {
  __shared__ __align__(16) _Float16 Ks[16][136];   // K' f16 scaled [i][j-local]
  __shared__ unsigned msc[16];
  __shared__ float Sred[16];

  const int tid  = threadIdx.x;
  const int js   = blockIdx.x;          // 0..7   (j block of 128)
  const int ib   = blockIdx.y;          // 0..63  (i block of 16)
  const int lane = tid & 63;
  const int w    = tid >> 6;            // wave 0..7
  const int g    = lane >> 4;           // k-group 0..3
  const int li   = lane & 15;

  const float fh = (float)hp[0];
  const float inv_h2 = 1.0f / (fh * fh);

  if (tid < 16) { msc[tid] = 0u; Sred[tid] = 0.0f; }
  __syncthreads();   // bar0: init visible before any wave's atomics (waves start together; cheap)

  // ---- issue ALL independent global loads up front (max MLP vs cold L2) ----
  // X fragments (B-operand of QK^T) + |x|^2
  const float* Xr = X + (size_t)(ib * 16 + li) * DD;
  f32x4 xa[4][2];
  #pragma unroll
  for (int kt = 0; kt < 4; ++kt) {
    int d0 = kt * 32 + g * 8;
    xa[kt][0] = *(const f32x4*)(Xr + d0);
    xa[kt][1] = *(const f32x4*)(Xr + d0 + 4);
  }
  // phase-D B-operand prefetch: Y columns at d = dA, lane=li -> 64B runs
  const int dA = w * 16 + li;
  float bpre[4][8];
  #pragma unroll
  for (int kt = 0; kt < 4; ++kt) {
    const float* Yb = Y + (size_t)(js * 128 + kt * 32 + g * 8) * DD;
    #pragma unroll
    for (int e = 0; e < 8; ++e) bpre[kt][e] = Yb[e * DD + dA];
  }

  float xx = 0.f;
  #pragma unroll
  for (int kt = 0; kt < 4; ++kt)
    #pragma unroll
    for (int c = 0; c < 4; ++c)
      xx += xa[kt][0][c] * xa[kt][0][c] + xa[kt][1][c] * xa[kt][1][c];
  xx += __shfl_xor(xx, 16); xx += __shfl_xor(xx, 32);

  // ---- Phase A: QK^T over own 16-j window; |y|^2 in-register ----
  const float* Yr = Y + (size_t)(js * 128 + w * 16 + li) * DD;
  f32x4 acc = {0.f, 0.f, 0.f, 0.f};
  float yy = 0.f;
  #pragma unroll
  for (int kt = 0; kt < 4; ++kt) {
    int d0 = kt * 32 + g * 8;
    f32x4 a0 = *(const f32x4*)(Yr + d0), a1 = *(const f32x4*)(Yr + d0 + 4);
    #pragma unroll
    for (int c = 0; c < 4; ++c) yy += a0[c] * a0[c] + a1[c] * a1[c];
    acc = __builtin_amdgcn_mfma_f32_16x16x32_f16(cvt8(a0, a1),
                                                 cvt8(xa[kt][0], xa[kt][1]), acc, 0, 0, 0);
  }
  yy += __shfl_xor(yy, 16); yy += __shfl_xor(yy, 32);   // full row-norm on every lane of its li-class

  // ---- exp: K[r] = K[j = w*16+4g+r][i = li]; row norms via wave-local shfl ----
  float K[4];
  float m = 0.f, sp = 0.f;
  #pragma unroll
  for (int r = 0; r < 4; ++r) {
    float yyj = __shfl(yy, 4 * g + r);     // lane 4g+r holds norm of row w*16+4g+r
    float e = fminf((acc[r] - 0.5f * (xx + yyj)) * inv_h2, 0.0f);
    K[r] = exp2f(e * 1.44269504088896341f);
    m = fmaxf(m, K[r]); sp += K[r];
  }
  // K store: rows=li, 4 g-quads per row -> full 64B segments
  {
    float* kb = out + (size_t)(ib * 16 + li) * NN + js * 128 + w * 16 + 4 * g;
    f32x4 kv = { K[0], K[1], K[2], K[3] };
    *(f32x4*)kb = kv;
  }
  // per-i stats over this wave's 16 j, then block-wide via LDS atomics
  m = fmaxf(m, __shfl_xor(m, 16)); m = fmaxf(m, __shfl_xor(m, 32));
  sp += __shfl_xor(sp, 16);        sp += __shfl_xor(sp, 32);
  if (lane < 16) {
    atomicMax(&msc[li], __float_as_uint(m));
    atomicAdd(&Sred[li], sp);
  }
  __syncthreads();   // bar1: msc/Sred final

  if (tid < 16) ws[(size_t)js * NN + ib * 16 + tid] = Sred[tid];

  // ---- scaled K' (f16) into Ks[i][j-local] ----
  {
    unsigned ue = (msc[li] >> 23) & 0xffu;
    unsigned se = 266u - ue; if (se > 254u) se = 254u;  // K'max in [2^12,2^13)
    float scale = __uint_as_float(se << 23);
    f16x4 q;
    #pragma unroll
    for (int r = 0; r < 4; ++r) q[r] = (_Float16)(K[r] * scale);
    *(f16x4*)&Ks[li][w * 16 + 4 * g] = q;
  }
  __syncthreads();   // bar2: Ks ready

  // ---- Phase D: D[i][dA] = sum_{j=0..127} K'[i][j] * Y[j][dA] ----
  f32x4 c0 = {0.f, 0.f, 0.f, 0.f};
  #pragma unroll
  for (int kt = 0; kt < 4; ++kt) {
    f16x8 afK = *(const f16x8*)&Ks[li][kt * 32 + g * 8];   // A[m=i=li][k=j]
    f16x8 b0;
    #pragma unroll
    for (int e = 0; e < 8; ++e) b0[e] = (_Float16)bpre[kt][e];  // B[k=j][n -> d=dA]
    c0 = __builtin_amdgcn_mfma_f32_16x16x32_f16(afK, b0, c0, 0, 0, 0);
  }

  // ---- epilogue: unscale, coalesced private-slab stores (64B runs) ----
  float* pb = ws + WS_PART + (size_t)js * (NN * DD) + (size_t)(ib * 16) * DD;
  #pragma unroll
  for (int r = 0; r < 4; ++r) {
    int il = 4 * g + r;
    unsigned ue2 = (msc[il] >> 23) & 0xffu;
    unsigned se2 = 266u - ue2; if (se2 > 254u) se2 = 254u;
    float invs = __uint_as_float((254u - se2) << 23);   // 1/scale for row il
    pb[il * DD + dA] = c0[r] * invs;
  }
}

// dK[i][d] = inv_h2 * (sum_js part[js][i][d] - (sum_js S[js][i]) * X[i][d])
__global__ __launch_bounds__(256) void dk_reduce(const float* __restrict__ X,
                                                 const int* __restrict__ hp,
                                                 const float* __restrict__ ws,
                                                 float* __restrict__ out) {
  const int unit = blockIdx.x * 256 + threadIdx.x;   // 0..32767 (f32x4 units)
  const int i  = unit >> 5;
  const int d0 = (unit & 31) * 4;
  const float fh = (float)hp[0];
  const float inv_h2 = 1.0f / (fh * fh);

  f32x4 acc = {0.f, 0.f, 0.f, 0.f};
  float s = 0.f;
  #pragma unroll
  for (int js = 0; js < 8; ++js) {
    f32x4 p = *(const f32x4*)(ws + WS_PART + (size_t)js * (NN * DD) + (size_t)i * DD + d0);
    acc.x += p.x; acc.y += p.y; acc.z += p.z; acc.w += p.w;
    s += ws[(size_t)js * NN + i];
  }
  f32x4 xv = *(const f32x4*)(X + (size_t)i * DD + d0);
  f32x4 r;
  r.x = (acc.x - s * xv.x) * inv_h2;
  r.y = (acc.y - s * xv.y) * inv_h2;
  r.z = (acc.z - s * xv.z) * inv_h2;
  r.w = (acc.w - s * xv.w) * inv_h2;
  *(f32x4*)(out + (size_t)NN * NN + (size_t)i * DD + d0) = r;
}

extern "C" void kernel_launch(void* const* d_in, const int* in_sizes, int n_in,
                              void* d_out, int out_size, void* d_ws, size_t ws_size,
                              hipStream_t stream) {
  const float* X  = (const float*)d_in[0];
  const float* Y  = (const float*)d_in[1];
  const int*   hp = (const int*)d_in[2];
  float* out = (float*)d_out;
  float* ws  = (float*)d_ws;    // needs (8192 + 1048576) f32 ≈ 4.2 MB

  hipLaunchKernelGGL(gk_main, dim3(8, 64), dim3(512), 0, stream, X, Y, hp, out, ws);
  hipLaunchKernelGGL(dk_reduce, dim3(128), dim3(256), 0, stream, X, hp, ws, out);
}

// Round 10
// 18.063 us; speedup vs baseline: 1.2217x; 1.0827x over previous
//
#include <hip/hip_runtime.h>

#define NN 1024
#define DD 128

typedef float f32x4 __attribute__((ext_vector_type(4)));
typedef _Float16 f16x4 __attribute__((ext_vector_type(4)));
typedef _Float16 f16x8 __attribute__((ext_vector_type(8)));

__device__ __forceinline__ f16x8 cvt8(f32x4 a, f32x4 b) {
  f16x8 r;
  r[0] = (_Float16)a.x; r[1] = (_Float16)a.y; r[2] = (_Float16)a.z; r[3] = (_Float16)a.w;
  r[4] = (_Float16)b.x; r[5] = (_Float16)b.y; r[6] = (_Float16)b.z; r[7] = (_Float16)b.w;
  return r;
}

// ws layout (f32 units):
//   [0 .. 8192)            S[js][i]        (8 x 1024)
//   [8192 .. 8192+1048576) part[js][i][d]  (8 x 1024 x 128)
#define WS_PART 8192

// R4 structure (best known: grid (8 js, 64 ib), 256 thr = 4 waves, 16i x 128j
// tile, swapped QK^T, block-consistent per-i dynamic f16 scale, private ws
// slabs + dk_reduce). Two deltas vs R4:
//  1) LOAD ORDER: phase-A critical-path loads (X frags, Y rows) are issued
//     FIRST; the 64 scalar phase-D column loads (bpre) are issued AFTER the
//     QK^T MFMA loop. vmcnt drains in order, so in R4 phase A stalled behind
//     all 64 cold bpre gathers; now bpre latency hides under exp/barriers.
//  2) SLAB STORES: dK partials bounce through LDS and store as full-line
//     512B runs instead of 64B partial-line RFO scatter.
__global__ __launch_bounds__(256, 2) void gk_main(const float* __restrict__ X,
                                                  const float* __restrict__ Y,
                                                  const int* __restrict__ hp,
                                                  float* __restrict__ out,
                                                  float* __restrict__ ws) {
  __shared__ __align__(16) _Float16 Ks[16][136];   // K' f16 scaled
  __shared__ __align__(16) float dkw[16][128];     // dK partial bounce (8 KB)
  __shared__ float yys[128];
  __shared__ unsigned msc[16];
  __shared__ float Sred[16];

  const int tid  = threadIdx.x;
  const int js   = blockIdx.x;          // 0..7   (j block of 128)
  const int ib   = blockIdx.y;          // 0..63  (i block of 16)
  const int lane = tid & 63;
  const int w    = tid >> 6;            // wave 0..3
  const int g    = lane >> 4;           // k-group 0..3
  const int li   = lane & 15;

  const float fh = (float)hp[0];
  const float inv_h2 = 1.0f / (fh * fh);

  if (tid < 16) { msc[tid] = 0u; Sred[tid] = 0.0f; }

  // ---- critical-path loads FIRST: X fragments + all 16 Y-row vectors ----
  const float* Xr = X + (size_t)(ib * 16 + li) * DD;
  f32x4 xa[4][2];
  #pragma unroll
  for (int kt = 0; kt < 4; ++kt) {
    int d0 = kt * 32 + g * 8;
    xa[kt][0] = *(const f32x4*)(Xr + d0);
    xa[kt][1] = *(const f32x4*)(Xr + d0 + 4);
  }
  const float* Yr0 = Y + (size_t)(js * 128 + w * 32 + li) * DD;
  const float* Yr1 = Yr0 + 16 * DD;
  f32x4 ya0[4][2], ya1[4][2];
  #pragma unroll
  for (int kt = 0; kt < 4; ++kt) {
    int d0 = kt * 32 + g * 8;
    ya0[kt][0] = *(const f32x4*)(Yr0 + d0);
    ya0[kt][1] = *(const f32x4*)(Yr0 + d0 + 4);
    ya1[kt][0] = *(const f32x4*)(Yr1 + d0);
    ya1[kt][1] = *(const f32x4*)(Yr1 + d0 + 4);
  }

  float xx = 0.f;
  #pragma unroll
  for (int kt = 0; kt < 4; ++kt)
    #pragma unroll
    for (int c = 0; c < 4; ++c)
      xx += xa[kt][0][c] * xa[kt][0][c] + xa[kt][1][c] * xa[kt][1][c];
  xx += __shfl_xor(xx, 16); xx += __shfl_xor(xx, 32);

  // ---- Phase A: QK^T MFMAs + |y|^2 from the preloaded Y rows ----
  f32x4 acc0 = {0.f, 0.f, 0.f, 0.f}, acc1 = {0.f, 0.f, 0.f, 0.f};
  float yy0 = 0.f, yy1 = 0.f;
  #pragma unroll
  for (int kt = 0; kt < 4; ++kt) {
    #pragma unroll
    for (int c = 0; c < 4; ++c) {
      yy0 += ya0[kt][0][c] * ya0[kt][0][c] + ya0[kt][1][c] * ya0[kt][1][c];
      yy1 += ya1[kt][0][c] * ya1[kt][0][c] + ya1[kt][1][c] * ya1[kt][1][c];
    }
    f16x8 bf = cvt8(xa[kt][0], xa[kt][1]);
    acc0 = __builtin_amdgcn_mfma_f32_16x16x32_f16(cvt8(ya0[kt][0], ya0[kt][1]), bf, acc0, 0, 0, 0);
    acc1 = __builtin_amdgcn_mfma_f32_16x16x32_f16(cvt8(ya1[kt][0], ya1[kt][1]), bf, acc1, 0, 0, 0);
  }

  // ---- NOW issue the phase-D column prefetch (consumed only after bar3) ----
  const int dA = w * 32 + li;
  const int dB = dA + 16;
  float bpre0[4][8], bpre1[4][8];
  #pragma unroll
  for (int kt = 0; kt < 4; ++kt) {
    const float* Yb = Y + (size_t)(js * 128 + kt * 32 + g * 8) * DD;
    #pragma unroll
    for (int e = 0; e < 8; ++e) {
      bpre0[kt][e] = Yb[e * DD + dA];
      bpre1[kt][e] = Yb[e * DD + dB];
    }
  }

  yy0 += __shfl_xor(yy0, 16); yy0 += __shfl_xor(yy0, 32);
  yy1 += __shfl_xor(yy1, 16); yy1 += __shfl_xor(yy1, 32);
  if (lane < 16) { yys[w * 32 + lane] = yy0; yys[w * 32 + 16 + lane] = yy1; }
  __syncthreads();   // b1: yys ready, msc/Sred init visible

  // ---- exp: K = exp(inv_h2*(xy - 0.5(xx+yy))) clamped <= 1; stats in-reg ----
  float K[8];
  float m = 0.f, sp = 0.f;
  #pragma unroll
  for (int t = 0; t < 2; ++t) {
    f32x4 a = t ? acc1 : acc0;
    #pragma unroll
    for (int r = 0; r < 4; ++r) {
      int jl = w * 32 + t * 16 + 4 * g + r;
      float e = fminf((a[r] - 0.5f * (xx + yys[jl])) * inv_h2, 0.0f);
      float kv = exp2f(e * 1.44269504088896341f);
      K[t * 4 + r] = kv; m = fmaxf(m, kv); sp += kv;
    }
  }
  // K store: per instr, 4 g-lanes x 16 li-rows cover full 128B lines pairwise
  {
    float* kb = out + (size_t)(ib * 16 + li) * NN + js * 128 + w * 32 + 4 * g;
    f32x4 k0 = { K[0], K[1], K[2], K[3] };
    f32x4 k1 = { K[4], K[5], K[6], K[7] };
    *(f32x4*)kb = k0;
    *(f32x4*)(kb + 16) = k1;
  }
  m = fmaxf(m, __shfl_xor(m, 16)); m = fmaxf(m, __shfl_xor(m, 32));
  sp += __shfl_xor(sp, 16);        sp += __shfl_xor(sp, 32);
  if (lane < 16) {
    atomicMax(&msc[li], __float_as_uint(m));
    atomicAdd(&Sred[li], sp);
  }
  __syncthreads();   // b2: msc, Sred complete

  if (tid < 16) ws[(size_t)js * NN + ib * 16 + tid] = Sred[tid];

  // ---- scaled K' (f16) for phase D ----
  {
    unsigned ue = (msc[li] >> 23) & 0xffu;
    unsigned se = 266u - ue; if (se > 254u) se = 254u;  // K'max in [2^12,2^13)
    float scale = __uint_as_float(se << 23);
    #pragma unroll
    for (int t = 0; t < 2; ++t) {
      f16x4 q;
      #pragma unroll
      for (int r = 0; r < 4; ++r) q[r] = (_Float16)(K[t * 4 + r] * scale);
      *(f16x4*)&Ks[li][w * 32 + t * 16 + 4 * g] = q;
    }
  }
  __syncthreads();   // b3: Ks ready

  // ---- Phase D: K' @ Y, B-operand from prefetched registers ----
  f32x4 c0 = {0.f, 0.f, 0.f, 0.f}, c1 = {0.f, 0.f, 0.f, 0.f};
  #pragma unroll
  for (int kt = 0; kt < 4; ++kt) {
    f16x8 af = *(const f16x8*)&Ks[li][kt * 32 + g * 8];
    f16x8 b0, b1;
    #pragma unroll
    for (int e = 0; e < 8; ++e) {
      b0[e] = (_Float16)bpre0[kt][e];
      b1[e] = (_Float16)bpre1[kt][e];
    }
    c0 = __builtin_amdgcn_mfma_f32_16x16x32_f16(af, b0, c0, 0, 0, 0);
    c1 = __builtin_amdgcn_mfma_f32_16x16x32_f16(af, b1, c1, 0, 0, 0);
  }

  // ---- epilogue: unscale into LDS bounce, then full-line slab stores ----
  #pragma unroll
  for (int r = 0; r < 4; ++r) {
    int il = 4 * g + r;
    unsigned ue2 = (msc[il] >> 23) & 0xffu;
    unsigned se2 = 266u - ue2; if (se2 > 254u) se2 = 254u;
    float invs = __uint_as_float((254u - se2) << 23);   // 1/scale for row il
    dkw[il][dA] = c0[r] * invs;
    dkw[il][dB] = c1[r] * invs;
  }
  __syncthreads();   // b4: dkw complete

  {
    int i = tid >> 4, s = tid & 15;
    f32x4 v0 = *(const f32x4*)&dkw[i][s * 8];
    f32x4 v1 = *(const f32x4*)&dkw[i][s * 8 + 4];
    float* pb = ws + WS_PART + (size_t)js * (NN * DD) + (size_t)(ib * 16 + i) * DD + s * 8;
    *(f32x4*)pb = v0;
    *(f32x4*)(pb + 4) = v1;
  }
}

// dK[i][d] = inv_h2 * (sum_js part[js][i][d] - (sum_js S[js][i]) * X[i][d])
__global__ __launch_bounds__(256) void dk_reduce(const float* __restrict__ X,
                                                 const int* __restrict__ hp,
                                                 const float* __restrict__ ws,
                                                 float* __restrict__ out) {
  const int unit = blockIdx.x * 256 + threadIdx.x;   // 0..32767 (f32x4 units)
  const int i  = unit >> 5;
  const int d0 = (unit & 31) * 4;
  const float fh = (float)hp[0];
  const float inv_h2 = 1.0f / (fh * fh);

  f32x4 acc = {0.f, 0.f, 0.f, 0.f};
  float s = 0.f;
  #pragma unroll
  for (int js = 0; js < 8; ++js) {
    f32x4 p = *(const f32x4*)(ws + WS_PART + (size_t)js * (NN * DD) + (size_t)i * DD + d0);
    acc.x += p.x; acc.y += p.y; acc.z += p.z; acc.w += p.w;
    s += ws[(size_t)js * NN + i];
  }
  f32x4 xv = *(const f32x4*)(X + (size_t)i * DD + d0);
  f32x4 r;
  r.x = (acc.x - s * xv.x) * inv_h2;
  r.y = (acc.y - s * xv.y) * inv_h2;
  r.z = (acc.z - s * xv.z) * inv_h2;
  r.w = (acc.w - s * xv.w) * inv_h2;
  *(f32x4*)(out + (size_t)NN * NN + (size_t)i * DD + d0) = r;
}

extern "C" void kernel_launch(void* const* d_in, const int* in_sizes, int n_in,
                              void* d_out, int out_size, void* d_ws, size_t ws_size,
                              hipStream_t stream) {
  const float* X  = (const float*)d_in[0];
  const float* Y  = (const float*)d_in[1];
  const int*   hp = (const int*)d_in[2];
  float* out = (float*)d_out;
  float* ws  = (float*)d_ws;    // needs (8192 + 1048576) f32 ≈ 4.2 MB

  hipLaunchKernelGGL(gk_main, dim3(8, 64), dim3(256), 0, stream, X, Y, hp, out, ws);
  hipLaunchKernelGGL(dk_reduce, dim3(128), dim3(256), 0, stream, X, hp, ws, out);
}

// Round 11
// 17.551 us; speedup vs baseline: 1.2574x; 1.0292x over previous
//
#include <hip/hip_runtime.h>

#define NN 1024
#define DD 128

typedef float f32x4 __attribute__((ext_vector_type(4)));
typedef _Float16 f16x4 __attribute__((ext_vector_type(4)));
typedef _Float16 f16x8 __attribute__((ext_vector_type(8)));

__device__ __forceinline__ f16x8 cvt8(f32x4 a, f32x4 b) {
  f16x8 r;
  r[0] = (_Float16)a.x; r[1] = (_Float16)a.y; r[2] = (_Float16)a.z; r[3] = (_Float16)a.w;
  r[4] = (_Float16)b.x; r[5] = (_Float16)b.y; r[6] = (_Float16)b.z; r[7] = (_Float16)b.w;
  return r;
}

// Raw workgroup barrier: LDS-visibility only (lgkmcnt), NO vmcnt(0) drain.
// __syncthreads() would force s_waitcnt vmcnt(0) and serialize every in-flight
// global load/store at each phase boundary (the campaign's hidden cost).
__device__ __forceinline__ void bar_lds() {
  asm volatile("s_waitcnt lgkmcnt(0)" ::: "memory");
  __builtin_amdgcn_s_barrier();
  asm volatile("" ::: "memory");
}

// ws layout (f32 units):
//   [0 .. 8192)            S[js][i]        (8 x 1024)
//   [8192 .. 8192+1048576) part[js][i][d]  (8 x 1024 x 128)
#define WS_PART 8192

// R4 structure (grid (8 js, 64 ib), 256 thr = 4 waves, 16i x 128j tile,
// swapped QK^T, block-consistent per-i dynamic f16 scale, private ws slabs).
// Deltas vs R4:
//  1) critical-path loads issued first, bpre after the QK^T MFMAs (R10)
//  2) ALL barriers are raw s_barrier + lgkmcnt-only -> bpre loads and K
//     stores stay in flight across phase boundaries (counted vmcnt at use)
//  3) y-norms via wave-local shfl (yys LDS + its barrier deleted)
__global__ __launch_bounds__(256, 2) void gk_main(const float* __restrict__ X,
                                                  const float* __restrict__ Y,
                                                  const int* __restrict__ hp,
                                                  float* __restrict__ out,
                                                  float* __restrict__ ws) {
  __shared__ __align__(16) _Float16 Ks[16][136];   // K' f16 scaled
  __shared__ unsigned msc[16];
  __shared__ float Sred[16];

  const int tid  = threadIdx.x;
  const int js   = blockIdx.x;          // 0..7   (j block of 128)
  const int ib   = blockIdx.y;          // 0..63  (i block of 16)
  const int lane = tid & 63;
  const int w    = tid >> 6;            // wave 0..3
  const int g    = lane >> 4;           // k-group 0..3
  const int li   = lane & 15;

  const float fh = (float)hp[0];
  const float inv_h2 = 1.0f / (fh * fh);

  // ---- critical-path loads FIRST: X fragments + all 16 Y-row vectors ----
  const float* Xr = X + (size_t)(ib * 16 + li) * DD;
  f32x4 xa[4][2];
  #pragma unroll
  for (int kt = 0; kt < 4; ++kt) {
    int d0 = kt * 32 + g * 8;
    xa[kt][0] = *(const f32x4*)(Xr + d0);
    xa[kt][1] = *(const f32x4*)(Xr + d0 + 4);
  }
  const float* Yr0 = Y + (size_t)(js * 128 + w * 32 + li) * DD;
  const float* Yr1 = Yr0 + 16 * DD;
  f32x4 ya0[4][2], ya1[4][2];
  #pragma unroll
  for (int kt = 0; kt < 4; ++kt) {
    int d0 = kt * 32 + g * 8;
    ya0[kt][0] = *(const f32x4*)(Yr0 + d0);
    ya0[kt][1] = *(const f32x4*)(Yr0 + d0 + 4);
    ya1[kt][0] = *(const f32x4*)(Yr1 + d0);
    ya1[kt][1] = *(const f32x4*)(Yr1 + d0 + 4);
  }

  // init AFTER load issue; raw barrier costs ~nothing here (all waves at start)
  if (tid < 16) { msc[tid] = 0u; Sred[tid] = 0.0f; }
  bar_lds();   // bar0: init visible before any wave's LDS atomics

  float xx = 0.f;
  #pragma unroll
  for (int kt = 0; kt < 4; ++kt)
    #pragma unroll
    for (int c = 0; c < 4; ++c)
      xx += xa[kt][0][c] * xa[kt][0][c] + xa[kt][1][c] * xa[kt][1][c];
  xx += __shfl_xor(xx, 16); xx += __shfl_xor(xx, 32);

  // ---- Phase A: QK^T MFMAs + |y|^2 from the preloaded Y rows ----
  f32x4 acc0 = {0.f, 0.f, 0.f, 0.f}, acc1 = {0.f, 0.f, 0.f, 0.f};
  float yy0 = 0.f, yy1 = 0.f;
  #pragma unroll
  for (int kt = 0; kt < 4; ++kt) {
    #pragma unroll
    for (int c = 0; c < 4; ++c) {
      yy0 += ya0[kt][0][c] * ya0[kt][0][c] + ya0[kt][1][c] * ya0[kt][1][c];
      yy1 += ya1[kt][0][c] * ya1[kt][0][c] + ya1[kt][1][c] * ya1[kt][1][c];
    }
    f16x8 bf = cvt8(xa[kt][0], xa[kt][1]);
    acc0 = __builtin_amdgcn_mfma_f32_16x16x32_f16(cvt8(ya0[kt][0], ya0[kt][1]), bf, acc0, 0, 0, 0);
    acc1 = __builtin_amdgcn_mfma_f32_16x16x32_f16(cvt8(ya1[kt][0], ya1[kt][1]), bf, acc1, 0, 0, 0);
  }

  // ---- phase-D column prefetch: stays in flight across bar1/bar2 ----
  const int dA = w * 32 + li;
  const int dB = dA + 16;
  float bpre0[4][8], bpre1[4][8];
  #pragma unroll
  for (int kt = 0; kt < 4; ++kt) {
    const float* Yb = Y + (size_t)(js * 128 + kt * 32 + g * 8) * DD;
    #pragma unroll
    for (int e = 0; e < 8; ++e) {
      bpre0[kt][e] = Yb[e * DD + dA];
      bpre1[kt][e] = Yb[e * DD + dB];
    }
  }

  // ---- y-norms wave-locally (no LDS, no barrier) ----
  yy0 += __shfl_xor(yy0, 16); yy0 += __shfl_xor(yy0, 32);   // row w*32+li
  yy1 += __shfl_xor(yy1, 16); yy1 += __shfl_xor(yy1, 32);   // row w*32+16+li

  // ---- exp: K = exp(inv_h2*(xy - 0.5(xx+yy))) clamped <= 1 ----
  float K[8];
  float m = 0.f, sp = 0.f;
  #pragma unroll
  for (int r = 0; r < 4; ++r) {
    float yj0 = __shfl(yy0, 4 * g + r);    // norm of row w*32 + 4g+r
    float yj1 = __shfl(yy1, 4 * g + r);    // norm of row w*32 + 16 + 4g+r
    float e0 = fminf((acc0[r] - 0.5f * (xx + yj0)) * inv_h2, 0.0f);
    float e1 = fminf((acc1[r] - 0.5f * (xx + yj1)) * inv_h2, 0.0f);
    K[r]     = exp2f(e0 * 1.44269504088896341f);
    K[4 + r] = exp2f(e1 * 1.44269504088896341f);
    m = fmaxf(m, fmaxf(K[r], K[4 + r]));
    sp += K[r] + K[4 + r];
  }
  // K store (in flight across bar1/bar2; drains only at kernel end)
  {
    float* kb = out + (size_t)(ib * 16 + li) * NN + js * 128 + w * 32 + 4 * g;
    f32x4 k0 = { K[0], K[1], K[2], K[3] };
    f32x4 k1 = { K[4], K[5], K[6], K[7] };
    *(f32x4*)kb = k0;
    *(f32x4*)(kb + 16) = k1;
  }
  m = fmaxf(m, __shfl_xor(m, 16)); m = fmaxf(m, __shfl_xor(m, 32));
  sp += __shfl_xor(sp, 16);        sp += __shfl_xor(sp, 32);
  if (lane < 16) {
    atomicMax(&msc[li], __float_as_uint(m));
    atomicAdd(&Sred[li], sp);
  }
  bar_lds();   // bar1: msc/Sred final (LDS only; bpre/K-stores NOT drained)

  if (tid < 16) ws[(size_t)js * NN + ib * 16 + tid] = Sred[tid];

  // ---- scaled K' (f16) for phase D ----
  {
    unsigned ue = (msc[li] >> 23) & 0xffu;
    unsigned se = 266u - ue; if (se > 254u) se = 254u;  // K'max in [2^12,2^13)
    float scale = __uint_as_float(se << 23);
    #pragma unroll
    for (int t = 0; t < 2; ++t) {
      f16x4 q;
      #pragma unroll
      for (int r = 0; r < 4; ++r) q[r] = (_Float16)(K[t * 4 + r] * scale);
      *(f16x4*)&Ks[li][w * 32 + t * 16 + 4 * g] = q;
    }
  }
  bar_lds();   // bar2: Ks ready (LDS only)

  // ---- Phase D: K' @ Y, B from prefetched regs (counted vmcnt at first use) ----
  f32x4 c0 = {0.f, 0.f, 0.f, 0.f}, c1 = {0.f, 0.f, 0.f, 0.f};
  #pragma unroll
  for (int kt = 0; kt < 4; ++kt) {
    f16x8 af = *(const f16x8*)&Ks[li][kt * 32 + g * 8];
    f16x8 b0, b1;
    #pragma unroll
    for (int e = 0; e < 8; ++e) {
      b0[e] = (_Float16)bpre0[kt][e];
      b1[e] = (_Float16)bpre1[kt][e];
    }
    c0 = __builtin_amdgcn_mfma_f32_16x16x32_f16(af, b0, c0, 0, 0, 0);
    c1 = __builtin_amdgcn_mfma_f32_16x16x32_f16(af, b1, c1, 0, 0, 0);
  }

  // ---- epilogue: unscale, private-slab stores (drain overlaps other blocks) ----
  float* pb = ws + WS_PART + (size_t)js * (NN * DD) + (size_t)(ib * 16) * DD;
  #pragma unroll
  for (int r = 0; r < 4; ++r) {
    int il = 4 * g + r;
    unsigned ue2 = (msc[il] >> 23) & 0xffu;
    unsigned se2 = 266u - ue2; if (se2 > 254u) se2 = 254u;
    float invs = __uint_as_float((254u - se2) << 23);   // 1/scale for row il
    pb[il * DD + dA] = c0[r] * invs;
    pb[il * DD + dB] = c1[r] * invs;
  }
}

// dK[i][d] = inv_h2 * (sum_js part[js][i][d] - (sum_js S[js][i]) * X[i][d])
__global__ __launch_bounds__(256) void dk_reduce(const float* __restrict__ X,
                                                 const int* __restrict__ hp,
                                                 const float* __restrict__ ws,
                                                 float* __restrict__ out) {
  const int unit = blockIdx.x * 256 + threadIdx.x;   // 0..32767 (f32x4 units)
  const int i  = unit >> 5;
  const int d0 = (unit & 31) * 4;
  const float fh = (float)hp[0];
  const float inv_h2 = 1.0f / (fh * fh);

  f32x4 acc = {0.f, 0.f, 0.f, 0.f};
  float s = 0.f;
  #pragma unroll
  for (int js = 0; js < 8; ++js) {
    f32x4 p = *(const f32x4*)(ws + WS_PART + (size_t)js * (NN * DD) + (size_t)i * DD + d0);
    acc.x += p.x; acc.y += p.y; acc.z += p.z; acc.w += p.w;
    s += ws[(size_t)js * NN + i];
  }
  f32x4 xv = *(const f32x4*)(X + (size_t)i * DD + d0);
  f32x4 r;
  r.x = (acc.x - s * xv.x) * inv_h2;
  r.y = (acc.y - s * xv.y) * inv_h2;
  r.z = (acc.z - s * xv.z) * inv_h2;
  r.w = (acc.w - s * xv.w) * inv_h2;
  *(f32x4*)(out + (size_t)NN * NN + (size_t)i * DD + d0) = r;
}

extern "C" void kernel_launch(void* const* d_in, const int* in_sizes, int n_in,
                              void* d_out, int out_size, void* d_ws, size_t ws_size,
                              hipStream_t stream) {
  const float* X  = (const float*)d_in[0];
  const float* Y  = (const float*)d_in[1];
  const int*   hp = (const int*)d_in[2];
  float* out = (float*)d_out;
  float* ws  = (float*)d_ws;    // needs (8192 + 1048576) f32 ≈ 4.2 MB

  hipLaunchKernelGGL(gk_main, dim3(8, 64), dim3(256), 0, stream, X, Y, hp, out, ws);
  hipLaunchKernelGGL(dk_reduce, dim3(128), dim3(256), 0, stream, X, hp, ws, out);
}